// Round 11
// baseline (2148.954 us; speedup 1.0000x reference)
//
#include <hip/hip_runtime.h>
#include <hip/hip_bf16.h>
#include <cmath>

#define N_NODES 8192
#define NFEAT 512
#define NHID 512
#define NCLASS 64
#define NLAYERS 8
#define CAP 96
#define NBLK 1024

typedef __attribute__((ext_vector_type(8))) short bf16x8;
typedef __attribute__((ext_vector_type(4))) float f32x4;
typedef unsigned short u16;

struct Coefs { float cA[8]; float cB[8]; };

__device__ inline float bf2f(short u) {
  union { unsigned int i; float f; } x;
  x.i = ((unsigned int)(u16)u) << 16;
  return x.f;
}
__device__ inline short f2bf(float f) {
  union { float f; unsigned int i; } x;
  x.f = f;
  unsigned int r = x.i + 0x7FFFu + ((x.i >> 16) & 1u);
  return (short)(r >> 16);
}

// ---------------- front: x->bf16 || weight transpose || extract --------------
// blocks [0,1024):      x f32->bf16 (16 MB)
// blocks [1024,3584):   weight transpose + GCNII identity fold (9.4 MB)
// blocks [3584,11776):  adjacency extraction (HBM-bound, 256 MB)
__global__ __launch_bounds__(256)
void front_kernel(const float* __restrict__ adj, int* __restrict__ idx,
                  int* __restrict__ cnt, int* __restrict__ colcnt,
                  const float* __restrict__ x, u16* __restrict__ xb,
                  const float* __restrict__ fc1W, const float* __restrict__ convW,
                  const float* __restrict__ fc2W,
                  u16* __restrict__ Wt, u16* __restrict__ Wt2, Coefs co)
{
  __shared__ char smraw[4224];
  const int bid = blockIdx.x;

  if (bid < 1024) {                    // ---- x -> bf16 ----
    const int base = bid * 256 + threadIdx.x;
    const float4* src = (const float4*)x;
    #pragma unroll
    for (int it = 0; it < 4; ++it) {
      const int i = it * (1024 * 256) + base;
      float4 v = src[i];
      ushort4 o;
      o.x = (u16)f2bf(v.x); o.y = (u16)f2bf(v.y);
      o.z = (u16)f2bf(v.z); o.w = (u16)f2bf(v.w);
      ((ushort4*)xb)[i] = o;
    }
    return;
  }

  if (bid < 3584) {                    // ---- weight transpose + fold ----
    float (*tile)[33] = (float(*)[33])smraw;
    const int vb = bid - 1024;
    const int m = vb >> 8;
    const int k0 = (vb & 15) * 32, n0 = ((vb >> 4) & 15) * 32;
    if (m == 9 && n0 >= 64) return;
    const int tx = threadIdx.x & 31, ty = threadIdx.x >> 5;  // 32 x 8
    if (m == 9) {
      #pragma unroll
      for (int r = 0; r < 32; r += 8)
        tile[ty + r][tx] = fc2W[(size_t)(k0 + ty + r) * 64 + n0 + tx];
      __syncthreads();
      #pragma unroll
      for (int r = 0; r < 32; r += 8)
        Wt2[(size_t)(n0 + ty + r) * 512 + k0 + tx] = (u16)f2bf(tile[tx][ty + r]);
      return;
    }
    const float* src = (m == 0) ? fc1W : convW + (size_t)(m - 1) * NHID * NHID;
    u16* dst = Wt + (size_t)m * NHID * NHID;
    float cA = 0.f, cB = 1.f;
    if (m >= 1) { cA = co.cA[m - 1]; cB = co.cB[m - 1]; }
    #pragma unroll
    for (int r = 0; r < 32; r += 8)
      tile[ty + r][tx] = src[(size_t)(k0 + ty + r) * NHID + n0 + tx];
    __syncthreads();
    #pragma unroll
    for (int r = 0; r < 32; r += 8) {
      const int krow = k0 + tx, ncol = n0 + ty + r;
      float val = cB * tile[tx][ty + r];
      if (m >= 1 && krow == ncol) val += cA;
      dst[(size_t)ncol * NHID + krow] = (u16)f2bf(val);
    }
    return;
  }

  // ---- extract row ----
  int* s_cnt = (int*)smraw;
  const int i = bid - 3584;
  if (threadIdx.x == 0) *s_cnt = 0;
  __syncthreads();
  const uint4* row = (const uint4*)(adj + (size_t)i * N_NODES);
  for (int c = threadIdx.x; c < N_NODES / 4; c += 256) {
    uint4 v = row[c];
    if ((v.x | v.y | v.z | v.w) == 0u) continue;   // 0.0f bit pattern is 0
    unsigned int vals[4] = {v.x, v.y, v.z, v.w};
    #pragma unroll
    for (int e = 0; e < 4; ++e) {
      if (vals[e] != 0u) {
        int p = atomicAdd(s_cnt, 1);
        if (p < CAP) idx[(size_t)i * CAP + p] = c * 4 + e;
        atomicAdd(&colcnt[c * 4 + e], 1);
      }
    }
  }
  __syncthreads();
  if (threadIdx.x == 0) cnt[i] = min(*s_cnt, CAP);
}

// ---------------- grid barrier (1024 co-resident blocks, r7-proven) ---------
__device__ inline void gridbar(int* bar, int phase) {
  __syncthreads();
  if (threadIdx.x == 0) {
    __hip_atomic_fetch_add(&bar[phase], 1, __ATOMIC_RELEASE, __HIP_MEMORY_SCOPE_AGENT);
    while (__hip_atomic_load(&bar[phase], __ATOMIC_RELAXED, __HIP_MEMORY_SCOPE_AGENT) < NBLK)
      __builtin_amdgcn_s_sleep(2);
    __builtin_amdgcn_fence(__ATOMIC_ACQUIRE, "agent");  // invalidates this CU's L1
  }
  __syncthreads();
}

// ---------------- GEMM phase (r10's proven 2-buf counted-vmcnt body) --------
#define AS1 __attribute__((address_space(1)))
#define AS3 __attribute__((address_space(3)))

__device__ inline void load16(const void* g, void* l) {
  __builtin_amdgcn_global_load_lds((const AS1 void*)g, (AS3 void*)l, 16, 0, 0);
}

// mode 0: v=relu(acc+bias); out0=H0, out1=Hs=dinv*v   [fc1]
// mode 1: v=relu(acc);      out0=Hs=dinv*v            [layers 0..6]
// mode 2: v=relu(acc);      out0=H (unscaled)         [layer 7]
__device__ void gemm_phase(const u16* __restrict__ A, const u16* __restrict__ Bt,
                           const float* __restrict__ bias, const int* __restrict__ colc,
                           u16* __restrict__ out0, u16* __restrict__ out1,
                           int mode, char* smem)
{
  constexpr int K = 512, N = 512;
  u16 (*lds)[2][64 * 64] = (u16(*)[2][64 * 64])smem;   // [buf][A/B][tile] 32 KB
  const int tid = threadIdx.x;
  const int wave = tid >> 6, lane = tid & 63;

  // chunked XCD swizzle: XCD = bid&7 = logical>>7; panel p read by XCD p>>4
  const int logical = (blockIdx.x & 7) * 128 + (blockIdx.x >> 3);
  const int m0 = (logical >> 3) * 64, n0 = (logical & 7) * 64;

  const int wr = wave >> 1, wc = wave & 1;
  const int lrow = lane & 15, lk = lane >> 4;

  f32x4 acc[2][2];
  #pragma unroll
  for (int a = 0; a < 2; ++a)
    #pragma unroll
    for (int b = 0; b < 2; ++b)
      acc[a][b] = (f32x4){0.f, 0.f, 0.f, 0.f};

  auto stage = [&](int b, int ks) {
    #pragma unroll
    for (int r = 0; r < 2; ++r) {
      const int c = r * 256 + wave * 64 + lane;   // 512 chunks of 16B per tile
      const int row = c >> 3;
      const int sc = (c & 7) ^ (row & 7);         // both-sides XOR swizzle
      load16(A  + (size_t)(m0 + row) * K + ks + sc * 8, &lds[b][0][(r * 256 + wave * 64) * 8]);
      load16(Bt + (size_t)(n0 + row) * K + ks + sc * 8, &lds[b][1][(r * 256 + wave * 64) * 8]);
    }
  };

  stage(0, 0);

  for (int t = 0; t < 8; ++t) {
    asm volatile("s_barrier" ::: "memory");            // WAR on buf (t+1)&1
    if (t + 1 < 8) {
      stage((t + 1) & 1, (t + 1) * 64);
      asm volatile("s_waitcnt vmcnt(4)" ::: "memory"); // own stage(t) landed
    } else {
      asm volatile("s_waitcnt vmcnt(0)" ::: "memory");
    }
    asm volatile("s_barrier" ::: "memory");            // RAW: whole buf t valid
    const int b = t & 1;
    const char* pA = (const char*)lds[b][0];
    const char* pB = (const char*)lds[b][1];
    bf16x8 af[2][2], bfr[2][2];
    #pragma unroll
    for (int mi = 0; mi < 2; ++mi) {
      const int row = wr * 32 + mi * 16 + lrow;
      #pragma unroll
      for (int ks2 = 0; ks2 < 2; ++ks2) {
        const int j = ks2 * 4 + lk;
        af[mi][ks2] = *(const bf16x8*)(pA + row * 128 + ((j ^ (row & 7)) * 16));
      }
    }
    #pragma unroll
    for (int ni = 0; ni < 2; ++ni) {
      const int row = wc * 32 + ni * 16 + lrow;
      #pragma unroll
      for (int ks2 = 0; ks2 < 2; ++ks2) {
        const int j = ks2 * 4 + lk;
        bfr[ni][ks2] = *(const bf16x8*)(pB + row * 128 + ((j ^ (row & 7)) * 16));
      }
    }
    #pragma unroll
    for (int ks2 = 0; ks2 < 2; ++ks2)
      #pragma unroll
      for (int mi = 0; mi < 2; ++mi)
        #pragma unroll
        for (int ni = 0; ni < 2; ++ni)
          acc[mi][ni] = __builtin_amdgcn_mfma_f32_16x16x32_bf16(af[mi][ks2], bfr[ni][ks2], acc[mi][ni], 0, 0, 0);
  }

  #pragma unroll
  for (int mi = 0; mi < 2; ++mi) {
    #pragma unroll
    for (int ni = 0; ni < 2; ++ni) {
      #pragma unroll
      for (int r = 0; r < 4; ++r) {
        const int row = m0 + wr * 32 + mi * 16 + lk * 4 + r;
        const int col = n0 + wc * 32 + ni * 16 + lrow;
        const size_t o = (size_t)row * N + col;
        float v = acc[mi][ni][r];
        if (mode == 0) {
          v = fmaxf(v + bias[col], 0.f);
          const float di = rsqrtf((float)colc[row] + 1.0f);
          out0[o] = (u16)f2bf(v);                 // H0
          out1[o] = (u16)f2bf(di * v);            // Hs
        } else if (mode == 1) {
          v = fmaxf(v, 0.f);
          const float di = rsqrtf((float)colc[row] + 1.0f);
          out0[o] = (u16)f2bf(di * v);
        } else {
          v = fmaxf(v, 0.f);
          out0[o] = (u16)f2bf(v);
        }
      }
    }
  }
}

// ---------------- SpMM phase: IR = 0.9*(P@H) + 0.1*H0 -----------------------
// Block bid: xcd = bid&7, q = bid>>3; panel p = 16*xcd + (q>>3) (so the GEMM
// blocks reading panel p — XCD p>>4 == xcd — find IR in their local L2);
// rows [p*64 + (q&7)*8, +8), wave handles 2 rows.
__device__ void spmm_phase(const u16* __restrict__ Hs, const u16* __restrict__ H0,
                           const int* __restrict__ colc, const int* __restrict__ idx,
                           const int* __restrict__ cnt, u16* __restrict__ IR)
{
  const int wave = threadIdx.x >> 6, lane = threadIdx.x & 63;
  const int xcd = blockIdx.x & 7, q = blockIdx.x >> 3;
  const int p = 16 * xcd + (q >> 3);
  const int row0 = p * 64 + (q & 7) * 8 + wave * 2;
  const int c0 = lane * 8;

  for (int rr = 0; rr < 2; ++rr) {
    const int i = row0 + rr;
    const int n = cnt[i];
    int jreg = 0;
    if (lane < n) jreg = idx[(size_t)i * CAP + lane] & (N_NODES - 1);
    float acc[8];
    #pragma unroll
    for (int e = 0; e < 8; ++e) acc[e] = 0.f;
    const int nn = min(n, 64);
    int t = 0;
    for (; t + 8 <= nn; t += 8) {                // 8 gathers in flight
      bf16x8 v[8];
      #pragma unroll
      for (int u = 0; u < 8; ++u) {
        const int j = __shfl(jreg, t + u);
        v[u] = *(const bf16x8*)&Hs[(size_t)j * NHID + c0];
      }
      #pragma unroll
      for (int u = 0; u < 8; ++u)
        #pragma unroll
        for (int e = 0; e < 8; ++e)
          acc[e] += bf2f(v[u][e]);
    }
    for (; t < nn; ++t) {
      const int j = __shfl(jreg, t);
      bf16x8 v = *(const bf16x8*)&Hs[(size_t)j * NHID + c0];
      #pragma unroll
      for (int e = 0; e < 8; ++e) acc[e] += bf2f(v[e]);
    }
    for (; t < n; ++t) {                         // n > 64: essentially never
      const int j = idx[(size_t)i * CAP + t] & (N_NODES - 1);
      bf16x8 v = *(const bf16x8*)&Hs[(size_t)j * NHID + c0];
      #pragma unroll
      for (int e = 0; e < 8; ++e) acc[e] += bf2f(v[e]);
    }
    const float di = rsqrtf((float)colc[i] + 1.0f);
    bf16x8 self = *(const bf16x8*)&Hs[(size_t)i * NHID + c0];
    bf16x8 h0   = *(const bf16x8*)&H0[(size_t)i * NHID + c0];
    bf16x8 ov;
    #pragma unroll
    for (int e = 0; e < 8; ++e) {
      float v = 0.9f * di * (acc[e] + bf2f(self[e])) + 0.1f * bf2f(h0[e]);
      ov[e] = f2bf(v);
    }
    *(bf16x8*)&IR[(size_t)i * NHID + c0] = ov;
  }
}

// ---------------- fc2 + -log_softmax phase (blocks 0..127) ------------------
__device__ void fc2_phase(const u16* __restrict__ A, const u16* __restrict__ Bt,
                          const float* __restrict__ bias, float* __restrict__ outF,
                          char* smem)
{
  constexpr int K = 512;
  u16 (*lds)[2][64 * 64] = (u16(*)[2][64 * 64])smem;
  const int tid = threadIdx.x;
  const int wave = tid >> 6, lane = tid & 63;
  const int m0 = blockIdx.x * 64;
  const int wr = wave >> 1, wc = wave & 1;
  const int lrow = lane & 15, lk = lane >> 4;

  f32x4 acc[2][2];
  #pragma unroll
  for (int a = 0; a < 2; ++a)
    #pragma unroll
    for (int b = 0; b < 2; ++b)
      acc[a][b] = (f32x4){0.f, 0.f, 0.f, 0.f};

  auto stage = [&](int b, int ks) {
    #pragma unroll
    for (int r = 0; r < 2; ++r) {
      const int c = r * 256 + wave * 64 + lane;
      const int row = c >> 3;
      const int sc = (c & 7) ^ (row & 7);
      load16(A  + (size_t)(m0 + row) * K + ks + sc * 8, &lds[b][0][(r * 256 + wave * 64) * 8]);
      load16(Bt + (size_t)row * K + ks + sc * 8,        &lds[b][1][(r * 256 + wave * 64) * 8]);
    }
  };

  stage(0, 0);

  for (int t = 0; t < 8; ++t) {
    asm volatile("s_barrier" ::: "memory");
    if (t + 1 < 8) {
      stage((t + 1) & 1, (t + 1) * 64);
      asm volatile("s_waitcnt vmcnt(4)" ::: "memory");
    } else {
      asm volatile("s_waitcnt vmcnt(0)" ::: "memory");
    }
    asm volatile("s_barrier" ::: "memory");
    const int b = t & 1;
    const char* pA = (const char*)lds[b][0];
    const char* pB = (const char*)lds[b][1];
    bf16x8 af[2][2], bfr[2][2];
    #pragma unroll
    for (int mi = 0; mi < 2; ++mi) {
      const int row = wr * 32 + mi * 16 + lrow;
      #pragma unroll
      for (int ks2 = 0; ks2 < 2; ++ks2) {
        const int j = ks2 * 4 + lk;
        af[mi][ks2] = *(const bf16x8*)(pA + row * 128 + ((j ^ (row & 7)) * 16));
      }
    }
    #pragma unroll
    for (int ni = 0; ni < 2; ++ni) {
      const int row = wc * 32 + ni * 16 + lrow;
      #pragma unroll
      for (int ks2 = 0; ks2 < 2; ++ks2) {
        const int j = ks2 * 4 + lk;
        bfr[ni][ks2] = *(const bf16x8*)(pB + row * 128 + ((j ^ (row & 7)) * 16));
      }
    }
    #pragma unroll
    for (int ks2 = 0; ks2 < 2; ++ks2)
      #pragma unroll
      for (int mi = 0; mi < 2; ++mi)
        #pragma unroll
        for (int ni = 0; ni < 2; ++ni)
          acc[mi][ni] = __builtin_amdgcn_mfma_f32_16x16x32_bf16(af[mi][ks2], bfr[ni][ks2], acc[mi][ni], 0, 0, 0);
  }

  __syncthreads();
  float* Cf = (float*)smem;                       // 64x65 f32
  #pragma unroll
  for (int mi = 0; mi < 2; ++mi)
    #pragma unroll
    for (int ni = 0; ni < 2; ++ni)
      #pragma unroll
      for (int r = 0; r < 4; ++r) {
        const int row = wr * 32 + mi * 16 + lk * 4 + r;
        const int cc = wc * 32 + ni * 16 + lrow;
        if (cc < NCLASS) Cf[row * 65 + cc] = acc[mi][ni][r] + bias[cc];
      }
  __syncthreads();
  #pragma unroll 4
  for (int r = 0; r < 16; ++r) {
    const int row = wave * 16 + r;
    const float v = Cf[row * 65 + lane];
    float mx = v;
    #pragma unroll
    for (int off = 32; off > 0; off >>= 1) mx = fmaxf(mx, __shfl_xor(mx, off));
    float s = __expf(v - mx);
    #pragma unroll
    for (int off = 32; off > 0; off >>= 1) s += __shfl_xor(s, off);
    outF[(size_t)(m0 + row) * NCLASS + lane] = -(v - mx - logf(s));
  }
}

// ---------------- single-dispatch pipeline: fc1 + 8 layers + fc2 ------------
__global__ __launch_bounds__(256, 4)   // 4 blocks/CU guaranteed: 1024 co-resident
void pipeline_kernel(const u16* __restrict__ xb, const u16* __restrict__ Wt,
                     const u16* __restrict__ Wt2,
                     const float* __restrict__ fc1b, const float* __restrict__ fc2b,
                     const int* __restrict__ colc, const int* __restrict__ idx,
                     const int* __restrict__ cnt,
                     u16* __restrict__ H0, u16* __restrict__ HsA, u16* __restrict__ HsB,
                     u16* __restrict__ IR, float* __restrict__ out,
                     int* __restrict__ bar)
{
  __shared__ char smem[32768];

  // fc1: H0 = relu(x@W+b), HsA = dinv*H0
  gemm_phase(xb, Wt, fc1b, colc, H0, HsA, 0, smem);
  gridbar(bar, 0);

  const u16* Hin = HsA;
  for (int l = 0; l < NLAYERS; ++l) {
    spmm_phase(Hin, H0, colc, idx, cnt, IR);
    gridbar(bar, 1 + 2 * l);
    u16* Hout = (l & 1) ? HsA : HsB;
    gemm_phase(IR, Wt + (size_t)(l + 1) * NHID * NHID, nullptr, colc,
               Hout, nullptr, (l < NLAYERS - 1) ? 1 : 2, smem);
    gridbar(bar, 2 + 2 * l);
    Hin = Hout;
  }

  if (blockIdx.x < 128)
    fc2_phase(Hin, Wt2, fc2b, out, smem);
}

// ---------------- launch -----------------------------------------------------
extern "C" void kernel_launch(void* const* d_in, const int* in_sizes, int n_in,
                              void* d_out, int out_size, void* d_ws, size_t ws_size,
                              hipStream_t stream)
{
  const float* x     = (const float*)d_in[0];
  const float* adj   = (const float*)d_in[1];
  const float* fc1W  = (const float*)d_in[2];
  const float* fc1b  = (const float*)d_in[3];
  const float* convW = (const float*)d_in[4];
  const float* fc2W  = (const float*)d_in[5];
  const float* fc2b  = (const float*)d_in[6];
  float* out = (float*)d_out;

  char* ws = (char*)d_ws;
  size_t off = 0;
  auto alloc = [&](size_t bytes) -> void* {
    void* p = ws + off;
    off = (off + bytes + 255) & ~(size_t)255;
    return p;
  };
  u16*   xb   = (u16*)alloc((size_t)N_NODES * NFEAT * 2);
  u16*   Wt   = (u16*)alloc((size_t)9 * NHID * NHID * 2);
  u16*   Wt2  = (u16*)alloc((size_t)NCLASS * NHID * 2);
  u16*   H0   = (u16*)alloc((size_t)N_NODES * NHID * 2);
  u16*   HsA  = (u16*)alloc((size_t)N_NODES * NHID * 2);
  u16*   HsB  = (u16*)alloc((size_t)N_NODES * NHID * 2);
  u16*   IR   = (u16*)alloc((size_t)N_NODES * NHID * 2);
  int*   idx  = (int*)alloc((size_t)N_NODES * CAP * 4);
  int*   cnt  = (int*)alloc((size_t)N_NODES * 4);
  int*   colc = (int*)alloc((size_t)N_NODES * 4);   // zeroed together with bar
  int*   bar  = (int*)alloc(128);                   // 17 phases used

  Coefs co;
  for (int i = 0; i < NLAYERS; ++i) {
    const double beta = log(0.5 / (double)(i + 1) + 1.0);
    co.cA[i] = (float)(1.0 - beta);
    co.cB[i] = (float)beta;
  }

  hipMemsetAsync(colc, 0, (size_t)N_NODES * 4 + 128, stream);
  front_kernel<<<1024 + 2560 + 8192, 256, 0, stream>>>(
      adj, idx, cnt, colc, x, xb, fc1W, convW, fc2W, Wt, Wt2, co);
  pipeline_kernel<<<NBLK, 256, 0, stream>>>(
      xb, Wt, Wt2, fc1b, fc2b, colc, idx, cnt, H0, HsA, HsB, IR, out, bar);
}

// Round 12
// 308.904 us; speedup vs baseline: 6.9567x; 6.9567x over previous
//
#include <hip/hip_runtime.h>
#include <hip/hip_bf16.h>
#include <cmath>

#define N_NODES 8192
#define NFEAT 512
#define NHID 512
#define NCLASS 64
#define NLAYERS 8
#define CAP 96

typedef __attribute__((ext_vector_type(8))) short bf16x8;
typedef __attribute__((ext_vector_type(4))) float f32x4;
typedef unsigned short u16;

struct Coefs { float cA[8]; float cB[8]; };

__device__ inline float bf2f(short u) {
  union { unsigned int i; float f; } x;
  x.i = ((unsigned int)(u16)u) << 16;
  return x.f;
}
__device__ inline short f2bf(float f) {
  union { float f; unsigned int i; } x;
  x.f = f;
  unsigned int r = x.i + 0x7FFFu + ((x.i >> 16) & 1u);
  return (short)(r >> 16);
}

// ---------------- prep: zero colc || x->bf16 || weight transpose ------------
// blocks [0,32):        colc = 0
// blocks [32,1056):     x f32->bf16 (16 MB)
// blocks [1056,3616):   weight transpose + GCNII identity fold (9.4 MB)
__global__ __launch_bounds__(256)
void prep_kernel(const float* __restrict__ x, u16* __restrict__ xb,
                 const float* __restrict__ fc1W, const float* __restrict__ convW,
                 const float* __restrict__ fc2W,
                 u16* __restrict__ Wt, u16* __restrict__ Wt2,
                 int* __restrict__ colc, Coefs co)
{
  __shared__ float tile[32][33];
  const int bid = blockIdx.x;

  if (bid < 32) {                      // ---- zero colc ----
    colc[bid * 256 + threadIdx.x] = 0;
    return;
  }

  if (bid < 1056) {                    // ---- x -> bf16 ----
    const int base = (bid - 32) * 256 + threadIdx.x;
    const float4* src = (const float4*)x;
    #pragma unroll
    for (int it = 0; it < 4; ++it) {
      const int i = it * (1024 * 256) + base;
      float4 v = src[i];
      ushort4 o;
      o.x = (u16)f2bf(v.x); o.y = (u16)f2bf(v.y);
      o.z = (u16)f2bf(v.z); o.w = (u16)f2bf(v.w);
      ((ushort4*)xb)[i] = o;
    }
    return;
  }

  // ---- weight transpose + identity fold ----
  // vb in [0,2560): m = vb>>8 (0=fc1, 1..8=conv layer, 9=fc2)
  const int vb = bid - 1056;
  const int m = vb >> 8;
  const int k0 = (vb & 15) * 32, n0 = ((vb >> 4) & 15) * 32;
  if (m == 9 && n0 >= 64) return;
  const int tx = threadIdx.x & 31, ty = threadIdx.x >> 5;  // 32 x 8
  if (m == 9) {
    #pragma unroll
    for (int r = 0; r < 32; r += 8)
      tile[ty + r][tx] = fc2W[(size_t)(k0 + ty + r) * 64 + n0 + tx];
    __syncthreads();
    #pragma unroll
    for (int r = 0; r < 32; r += 8)
      Wt2[(size_t)(n0 + ty + r) * 512 + k0 + tx] = (u16)f2bf(tile[tx][ty + r]);
    return;
  }
  const float* src = (m == 0) ? fc1W : convW + (size_t)(m - 1) * NHID * NHID;
  u16* dst = Wt + (size_t)m * NHID * NHID;
  float cA = 0.f, cB = 1.f;
  if (m >= 1) { cA = co.cA[m - 1]; cB = co.cB[m - 1]; }
  #pragma unroll
  for (int r = 0; r < 32; r += 8)
    tile[ty + r][tx] = src[(size_t)(k0 + ty + r) * NHID + n0 + tx];
  __syncthreads();
  #pragma unroll
  for (int r = 0; r < 32; r += 8) {
    const int krow = k0 + tx, ncol = n0 + ty + r;
    float val = cB * tile[tx][ty + r];
    if (m >= 1 && krow == ncol) val += cA;
    dst[(size_t)ncol * NHID + krow] = (u16)f2bf(val);
  }
}

// ---------------- GEMM body (r10's proven 2-buf counted-vmcnt) --------------
#define AS1 __attribute__((address_space(1)))
#define AS3 __attribute__((address_space(3)))

__device__ inline void load16(const void* g, void* l) {
  __builtin_amdgcn_global_load_lds((const AS1 void*)g, (AS3 void*)l, 16, 0, 0);
}

// mode 0: out0 = H0 = relu(acc+bias)                 [fc1 — NO colc dependency]
// mode 1: out0 = Hs = dinv*relu(acc)                 [layers 0..6]
// mode 2: out0 = H  = relu(acc)                      [layer 7]
// Pipeline per step t (2 bufs): B1 s_barrier (WAR) -> stage(t+1) ->
// s_waitcnt vmcnt(4) (own stage(t) landed) -> B2 s_barrier (RAW) -> compute(t).
template<int MODE>
__device__ void gemm_body(const u16* __restrict__ A, const u16* __restrict__ Bt,
                          const float* __restrict__ bias, const int* __restrict__ colc,
                          u16* __restrict__ out0, int m0, int n0, u16* lds_raw)
{
  constexpr int K = 512, N = 512;
  u16 (*lds)[2][64 * 64] = (u16(*)[2][64 * 64])lds_raw;   // [buf][A/B][tile] 32 KB
  const int tid = threadIdx.x;
  const int wave = tid >> 6, lane = tid & 63;
  const int wr = wave >> 1, wc = wave & 1;
  const int lrow = lane & 15, lk = lane >> 4;

  f32x4 acc[2][2];
  #pragma unroll
  for (int a = 0; a < 2; ++a)
    #pragma unroll
    for (int b = 0; b < 2; ++b)
      acc[a][b] = (f32x4){0.f, 0.f, 0.f, 0.f};

  // rows of 64 k = 128 B = 8 chunks of 16 B; XOR swizzle j^(row&7) folded into
  // the per-lane GLOBAL source chunk, LDS dest linear (both-sides rule).
  auto stage = [&](int b, int ks) {
    #pragma unroll
    for (int r = 0; r < 2; ++r) {
      const int c = r * 256 + wave * 64 + lane;   // 512 chunks of 16B per tile
      const int row = c >> 3;
      const int sc = (c & 7) ^ (row & 7);
      load16(A  + (size_t)(m0 + row) * K + ks + sc * 8, &lds[b][0][(r * 256 + wave * 64) * 8]);
      load16(Bt + (size_t)(n0 + row) * K + ks + sc * 8, &lds[b][1][(r * 256 + wave * 64) * 8]);
    }
  };

  stage(0, 0);

  for (int t = 0; t < 8; ++t) {
    asm volatile("s_barrier" ::: "memory");            // B1: WAR on buf (t+1)&1
    if (t + 1 < 8) {
      stage((t + 1) & 1, (t + 1) * 64);
      asm volatile("s_waitcnt vmcnt(4)" ::: "memory"); // own stage(t) landed
    } else {
      asm volatile("s_waitcnt vmcnt(0)" ::: "memory");
    }
    asm volatile("s_barrier" ::: "memory");            // B2: RAW — whole buf t valid
    const int b = t & 1;
    const char* pA = (const char*)lds[b][0];
    const char* pB = (const char*)lds[b][1];
    bf16x8 af[2][2], bfr[2][2];
    #pragma unroll
    for (int mi = 0; mi < 2; ++mi) {
      const int row = wr * 32 + mi * 16 + lrow;
      #pragma unroll
      for (int ks2 = 0; ks2 < 2; ++ks2) {
        const int j = ks2 * 4 + lk;
        af[mi][ks2] = *(const bf16x8*)(pA + row * 128 + ((j ^ (row & 7)) * 16));
      }
    }
    #pragma unroll
    for (int ni = 0; ni < 2; ++ni) {
      const int row = wc * 32 + ni * 16 + lrow;
      #pragma unroll
      for (int ks2 = 0; ks2 < 2; ++ks2) {
        const int j = ks2 * 4 + lk;
        bfr[ni][ks2] = *(const bf16x8*)(pB + row * 128 + ((j ^ (row & 7)) * 16));
      }
    }
    #pragma unroll
    for (int ks2 = 0; ks2 < 2; ++ks2)
      #pragma unroll
      for (int mi = 0; mi < 2; ++mi)
        #pragma unroll
        for (int ni = 0; ni < 2; ++ni)
          acc[mi][ni] = __builtin_amdgcn_mfma_f32_16x16x32_bf16(af[mi][ks2], bfr[ni][ks2], acc[mi][ni], 0, 0, 0);
  }

  #pragma unroll
  for (int mi = 0; mi < 2; ++mi) {
    #pragma unroll
    for (int ni = 0; ni < 2; ++ni) {
      #pragma unroll
      for (int r = 0; r < 4; ++r) {
        const int row = m0 + wr * 32 + mi * 16 + lk * 4 + r;
        const int col = n0 + wc * 32 + ni * 16 + lrow;
        const size_t o = (size_t)row * N + col;
        float v = acc[mi][ni][r];
        if (MODE == 0) {
          out0[o] = (u16)f2bf(fmaxf(v + bias[col], 0.f));       // H0 only
        } else if (MODE == 1) {
          v = fmaxf(v, 0.f);
          out0[o] = (u16)f2bf(rsqrtf((float)colc[row] + 1.0f) * v);
        } else {
          out0[o] = (u16)f2bf(fmaxf(v, 0.f));
        }
      }
    }
  }
}

// ---------------- mid: fc1 GEMM (H0 only) || adjacency extract --------------
// fc1 blocks [0,1024) read xb/Wt (from prep) and write H0 — independent of the
// extract blocks [1024,9216) which write idx/cnt/colc. fc1 hides under the
// extract's 256 MB HBM read.
__global__ __launch_bounds__(256)
void mid_kernel(const float* __restrict__ adj, int* __restrict__ idx,
                int* __restrict__ cnt, int* __restrict__ colcnt,
                const u16* __restrict__ xb, const u16* __restrict__ Wt,
                const float* __restrict__ fc1b, u16* __restrict__ H0)
{
  __shared__ u16 lds[2][2][64 * 64];   // 32 KB (GEMM path); extract reuses word 0
  const int bid = blockIdx.x;

  if (bid < 1024) {                    // ---- fc1 GEMM ----
    const int logical = (bid & 7) * 128 + (bid >> 3);    // chunked XCD swizzle
    const int m0 = (logical >> 3) * 64, n0 = (logical & 7) * 64;
    gemm_body<0>(xb, Wt, fc1b, nullptr, H0, m0, n0, &lds[0][0][0]);
    return;
  }

  // ---- extract row ----
  int* s_cnt = (int*)&lds[0][0][0];
  const int i = bid - 1024;
  if (threadIdx.x == 0) *s_cnt = 0;
  __syncthreads();
  const uint4* row = (const uint4*)(adj + (size_t)i * N_NODES);
  for (int c = threadIdx.x; c < N_NODES / 4; c += 256) {
    uint4 v = row[c];
    if ((v.x | v.y | v.z | v.w) == 0u) continue;   // 0.0f bit pattern is 0
    unsigned int vals[4] = {v.x, v.y, v.z, v.w};
    #pragma unroll
    for (int e = 0; e < 4; ++e) {
      if (vals[e] != 0u) {
        int p = atomicAdd(s_cnt, 1);
        if (p < CAP) idx[(size_t)i * CAP + p] = c * 4 + e;
        atomicAdd(&colcnt[c * 4 + e], 1);
      }
    }
  }
  __syncthreads();
  if (threadIdx.x == 0) cnt[i] = min(*s_cnt, CAP);
}

// ---------------- standalone layer GEMM --------------------------------------
template<int MODE>
__global__ __launch_bounds__(256, 4)
void gemm_kernel(const u16* __restrict__ A, const u16* __restrict__ Bt,
                 const int* __restrict__ colc, u16* __restrict__ out0)
{
  __shared__ u16 lds[2][2][64 * 64];
  const int logical = (blockIdx.x & 7) * 128 + (blockIdx.x >> 3);
  const int m0 = (logical >> 3) * 64, n0 = (logical & 7) * 64;
  gemm_body<MODE>(A, Bt, nullptr, colc, out0, m0, n0, &lds[0][0][0]);
}

// ---------------- fc2 + -log_softmax (MFMA, N=64) ---------------------------
__global__ __launch_bounds__(256, 4)
void fc2_kernel(const u16* __restrict__ A, const u16* __restrict__ Bt,
                const float* __restrict__ bias, float* __restrict__ outF)
{
  constexpr int K = 512;
  __shared__ u16 lds[2][2][64 * 64];   // 32 KB
  const int tid = threadIdx.x;
  const int wave = tid >> 6, lane = tid & 63;
  const int cpx = gridDim.x >> 3;
  const int logical = (blockIdx.x & 7) * cpx + (blockIdx.x >> 3);
  const int m0 = logical * 64;
  const int wr = wave >> 1, wc = wave & 1;
  const int lrow = lane & 15, lk = lane >> 4;

  f32x4 acc[2][2];
  #pragma unroll
  for (int a = 0; a < 2; ++a)
    #pragma unroll
    for (int b = 0; b < 2; ++b)
      acc[a][b] = (f32x4){0.f, 0.f, 0.f, 0.f};

  auto stage = [&](int b, int ks) {
    #pragma unroll
    for (int r = 0; r < 2; ++r) {
      const int c = r * 256 + wave * 64 + lane;
      const int row = c >> 3;
      const int sc = (c & 7) ^ (row & 7);
      load16(A  + (size_t)(m0 + row) * K + ks + sc * 8, &lds[b][0][(r * 256 + wave * 64) * 8]);
      load16(Bt + (size_t)row * K + ks + sc * 8,        &lds[b][1][(r * 256 + wave * 64) * 8]);
    }
  };

  stage(0, 0);

  for (int t = 0; t < 8; ++t) {
    asm volatile("s_barrier" ::: "memory");
    if (t + 1 < 8) {
      stage((t + 1) & 1, (t + 1) * 64);
      asm volatile("s_waitcnt vmcnt(4)" ::: "memory");
    } else {
      asm volatile("s_waitcnt vmcnt(0)" ::: "memory");
    }
    asm volatile("s_barrier" ::: "memory");
    const int b = t & 1;
    const char* pA = (const char*)lds[b][0];
    const char* pB = (const char*)lds[b][1];
    bf16x8 af[2][2], bfr[2][2];
    #pragma unroll
    for (int mi = 0; mi < 2; ++mi) {
      const int row = wr * 32 + mi * 16 + lrow;
      #pragma unroll
      for (int ks2 = 0; ks2 < 2; ++ks2) {
        const int j = ks2 * 4 + lk;
        af[mi][ks2] = *(const bf16x8*)(pA + row * 128 + ((j ^ (row & 7)) * 16));
      }
    }
    #pragma unroll
    for (int ni = 0; ni < 2; ++ni) {
      const int row = wc * 32 + ni * 16 + lrow;
      #pragma unroll
      for (int ks2 = 0; ks2 < 2; ++ks2) {
        const int j = ks2 * 4 + lk;
        bfr[ni][ks2] = *(const bf16x8*)(pB + row * 128 + ((j ^ (row & 7)) * 16));
      }
    }
    #pragma unroll
    for (int ks2 = 0; ks2 < 2; ++ks2)
      #pragma unroll
      for (int mi = 0; mi < 2; ++mi)
        #pragma unroll
        for (int ni = 0; ni < 2; ++ni)
          acc[mi][ni] = __builtin_amdgcn_mfma_f32_16x16x32_bf16(af[mi][ks2], bfr[ni][ks2], acc[mi][ni], 0, 0, 0);
  }

  __syncthreads();
  float* Cf = (float*)&lds[0][0][0];              // 64x65 f32
  #pragma unroll
  for (int mi = 0; mi < 2; ++mi)
    #pragma unroll
    for (int ni = 0; ni < 2; ++ni)
      #pragma unroll
      for (int r = 0; r < 4; ++r) {
        const int row = wr * 32 + mi * 16 + lk * 4 + r;
        const int cc = wc * 32 + ni * 16 + lrow;
        if (cc < NCLASS) Cf[row * 65 + cc] = acc[mi][ni][r] + bias[cc];
      }
  __syncthreads();
  #pragma unroll 4
  for (int r = 0; r < 16; ++r) {
    const int row = wave * 16 + r;
    const float v = Cf[row * 65 + lane];
    float mx = v;
    #pragma unroll
    for (int off = 32; off > 0; off >>= 1) mx = fmaxf(mx, __shfl_xor(mx, off));
    float s = __expf(v - mx);
    #pragma unroll
    for (int off = 32; off > 0; off >>= 1) s += __shfl_xor(s, off);
    outF[(size_t)(m0 + row) * NCLASS + lane] = -(v - mx - logf(s));
  }
}

// ---------------- SpMM: IR = 0.9*(P@H) + 0.1*H0 -----------------------------
// FIRST=1: H is unscaled H0; per-neighbor weight rsqrtf(colc[j]+1) — the colc[j]
// load is PARALLEL to the row gather (both depend only on j), not a chain.
// FIRST=0: H is pre-scaled Hs (weights folded in).
template<int FIRST>
__global__ __launch_bounds__(256)
void spmm_kernel(const u16* __restrict__ H, const u16* __restrict__ H0,
                 const int* __restrict__ colc, const int* __restrict__ idx,
                 const int* __restrict__ cnt, u16* __restrict__ IR)
{
  const int wave = threadIdx.x >> 6, lane = threadIdx.x & 63;
  const int i = blockIdx.x * 4 + wave;
  const int c0 = lane * 8;
  const int n = cnt[i];
  int jreg = 0;
  if (lane < n) jreg = idx[(size_t)i * CAP + lane] & (N_NODES - 1);

  float acc[8];
  #pragma unroll
  for (int e = 0; e < 8; ++e) acc[e] = 0.f;

  const int nn = min(n, 64);
  int t = 0;
  for (; t + 8 <= nn; t += 8) {          // 8 gathers in flight
    bf16x8 v[8];
    float w[8];
    #pragma unroll
    for (int u = 0; u < 8; ++u) {
      const int j = __shfl(jreg, t + u);
      v[u] = *(const bf16x8*)&H[(size_t)j * NHID + c0];
      if (FIRST) w[u] = (float)colc[j];
    }
    #pragma unroll
    for (int u = 0; u < 8; ++u) {
      const float ww = FIRST ? rsqrtf(w[u] + 1.0f) : 1.0f;
      #pragma unroll
      for (int e = 0; e < 8; ++e)
        acc[e] += ww * bf2f(v[u][e]);
    }
  }
  for (; t < nn; ++t) {
    const int j = __shfl(jreg, t);
    bf16x8 v = *(const bf16x8*)&H[(size_t)j * NHID + c0];
    const float ww = FIRST ? rsqrtf((float)colc[j] + 1.0f) : 1.0f;
    #pragma unroll
    for (int e = 0; e < 8; ++e) acc[e] += ww * bf2f(v[e]);
  }
  for (; t < n; ++t) {                   // n > 64: essentially never
    const int j = idx[(size_t)i * CAP + t] & (N_NODES - 1);
    bf16x8 v = *(const bf16x8*)&H[(size_t)j * NHID + c0];
    const float ww = FIRST ? rsqrtf((float)colc[j] + 1.0f) : 1.0f;
    #pragma unroll
    for (int e = 0; e < 8; ++e) acc[e] += ww * bf2f(v[e]);
  }

  const float di = rsqrtf((float)colc[i] + 1.0f);
  bf16x8 ov;
  if (FIRST) {
    bf16x8 self = *(const bf16x8*)&H[(size_t)i * NHID + c0];   // == H0 row
    #pragma unroll
    for (int e = 0; e < 8; ++e) {
      const float s = bf2f(self[e]);
      ov[e] = f2bf(0.9f * di * (acc[e] + di * s) + 0.1f * s);
    }
  } else {
    bf16x8 self = *(const bf16x8*)&H[(size_t)i * NHID + c0];
    bf16x8 h0   = *(const bf16x8*)&H0[(size_t)i * NHID + c0];
    #pragma unroll
    for (int e = 0; e < 8; ++e) {
      float v = 0.9f * di * (acc[e] + bf2f(self[e])) + 0.1f * bf2f(h0[e]);
      ov[e] = f2bf(v);
    }
  }
  *(bf16x8*)&IR[(size_t)i * NHID + c0] = ov;
}

// ---------------- launch -----------------------------------------------------
extern "C" void kernel_launch(void* const* d_in, const int* in_sizes, int n_in,
                              void* d_out, int out_size, void* d_ws, size_t ws_size,
                              hipStream_t stream)
{
  const float* x     = (const float*)d_in[0];
  const float* adj   = (const float*)d_in[1];
  const float* fc1W  = (const float*)d_in[2];
  const float* fc1b  = (const float*)d_in[3];
  const float* convW = (const float*)d_in[4];
  const float* fc2W  = (const float*)d_in[5];
  const float* fc2b  = (const float*)d_in[6];
  float* out = (float*)d_out;

  char* ws = (char*)d_ws;
  size_t off = 0;
  auto alloc = [&](size_t bytes) -> void* {
    void* p = ws + off;
    off = (off + bytes + 255) & ~(size_t)255;
    return p;
  };
  u16*   xb   = (u16*)alloc((size_t)N_NODES * NFEAT * 2);
  u16*   Wt   = (u16*)alloc((size_t)9 * NHID * NHID * 2);
  u16*   Wt2  = (u16*)alloc((size_t)NCLASS * NHID * 2);
  u16*   H0   = (u16*)alloc((size_t)N_NODES * NHID * 2);
  u16*   HsA  = (u16*)alloc((size_t)N_NODES * NHID * 2);
  u16*   HsB  = (u16*)alloc((size_t)N_NODES * NHID * 2);
  u16*   IR   = (u16*)alloc((size_t)N_NODES * NHID * 2);
  int*   idx  = (int*)alloc((size_t)N_NODES * CAP * 4);
  int*   cnt  = (int*)alloc((size_t)N_NODES * 4);
  int*   colc = (int*)alloc((size_t)N_NODES * 4);

  Coefs co;
  for (int i = 0; i < NLAYERS; ++i) {
    const double beta = log(0.5 / (double)(i + 1) + 1.0);
    co.cA[i] = (float)(1.0 - beta);
    co.cB[i] = (float)beta;
  }

  // prep: colc=0 || x->bf16 || weight transpose+fold
  prep_kernel<<<32 + 1024 + 2560, 256, 0, stream>>>(
      x, xb, fc1W, convW, fc2W, Wt, Wt2, colc, co);

  // mid: fc1 (H0 only, hides under extract) || adjacency extract
  mid_kernel<<<1024 + 8192, 256, 0, stream>>>(
      adj, idx, cnt, colc, xb, Wt, fc1b, H0);

  const u16* Hin = H0;
  for (int l = 0; l < NLAYERS; ++l) {
    if (l == 0)
      spmm_kernel<1><<<N_NODES / 4, 256, 0, stream>>>(Hin, H0, colc, idx, cnt, IR);
    else
      spmm_kernel<0><<<N_NODES / 4, 256, 0, stream>>>(Hin, H0, colc, idx, cnt, IR);
    u16* Hout = (l & 1) ? HsB : HsA;
    if (l < NLAYERS - 1)
      gemm_kernel<1><<<1024, 256, 0, stream>>>(
          IR, Wt + (size_t)(l + 1) * NHID * NHID, colc, Hout);
    else
      gemm_kernel<2><<<1024, 256, 0, stream>>>(
          IR, Wt + (size_t)(l + 1) * NHID * NHID, colc, Hout);
    Hin = Hout;
  }

  // fc2 + -log_softmax (MFMA, N=64)
  fc2_kernel<<<128, 256, 0, stream>>>(Hin, Wt2, fc2b, out);
}

// Round 13
// 305.395 us; speedup vs baseline: 7.0366x; 1.0115x over previous
//
#include <hip/hip_runtime.h>
#include <hip/hip_bf16.h>
#include <cmath>

#define N_NODES 8192
#define NFEAT 512
#define NHID 512
#define NCLASS 64
#define NLAYERS 8
#define CAP 96

typedef __attribute__((ext_vector_type(8))) short bf16x8;
typedef __attribute__((ext_vector_type(4))) float f32x4;
typedef unsigned short u16;

struct Coefs { float cA[8]; float cB[8]; };

__device__ inline float bf2f(short u) {
  union { unsigned int i; float f; } x;
  x.i = ((unsigned int)(u16)u) << 16;
  return x.f;
}
__device__ inline short f2bf(float f) {
  union { float f; unsigned int i; } x;
  x.f = f;
  unsigned int r = x.i + 0x7FFFu + ((x.i >> 16) & 1u);
  return (short)(r >> 16);
}

// ---------------- front: x->bf16 || weight transpose || extract --------------
// Small jobs FIRST so they overlap the extract ramp:
// blocks [0,1024):      x f32->bf16 (16 MB)
// blocks [1024,3584):   weight transpose + GCNII identity fold (9.4 MB)
// blocks [3584,11776):  adjacency extraction (HBM-bound, 256 MB)
__global__ __launch_bounds__(256)
void front_kernel(const float* __restrict__ adj, int* __restrict__ idx,
                  int* __restrict__ cnt, int* __restrict__ colcnt,
                  const float* __restrict__ x, u16* __restrict__ xb,
                  const float* __restrict__ fc1W, const float* __restrict__ convW,
                  const float* __restrict__ fc2W,
                  u16* __restrict__ Wt, u16* __restrict__ Wt2, Coefs co)
{
  __shared__ char smraw[4224];
  const int bid = blockIdx.x;

  if (bid < 1024) {                    // ---- x -> bf16 ----
    const int base = bid * 256 + threadIdx.x;
    const float4* src = (const float4*)x;
    #pragma unroll
    for (int it = 0; it < 4; ++it) {
      const int i = it * (1024 * 256) + base;
      float4 v = src[i];
      ushort4 o;
      o.x = (u16)f2bf(v.x); o.y = (u16)f2bf(v.y);
      o.z = (u16)f2bf(v.z); o.w = (u16)f2bf(v.w);
      ((ushort4*)xb)[i] = o;
    }
    return;
  }

  if (bid < 3584) {                    // ---- weight transpose + fold ----
    // vb in [0,2560): m = vb>>8 (0=fc1, 1..8=conv layer, 9=fc2)
    float (*tile)[33] = (float(*)[33])smraw;
    const int vb = bid - 1024;
    const int m = vb >> 8;
    const int k0 = (vb & 15) * 32, n0 = ((vb >> 4) & 15) * 32;
    if (m == 9 && n0 >= 64) return;
    const int tx = threadIdx.x & 31, ty = threadIdx.x >> 5;  // 32 x 8
    if (m == 9) {
      #pragma unroll
      for (int r = 0; r < 32; r += 8)
        tile[ty + r][tx] = fc2W[(size_t)(k0 + ty + r) * 64 + n0 + tx];
      __syncthreads();
      #pragma unroll
      for (int r = 0; r < 32; r += 8)
        Wt2[(size_t)(n0 + ty + r) * 512 + k0 + tx] = (u16)f2bf(tile[tx][ty + r]);
      return;
    }
    const float* src = (m == 0) ? fc1W : convW + (size_t)(m - 1) * NHID * NHID;
    u16* dst = Wt + (size_t)m * NHID * NHID;
    float cA = 0.f, cB = 1.f;
    if (m >= 1) { cA = co.cA[m - 1]; cB = co.cB[m - 1]; }
    #pragma unroll
    for (int r = 0; r < 32; r += 8)
      tile[ty + r][tx] = src[(size_t)(k0 + ty + r) * NHID + n0 + tx];
    __syncthreads();
    #pragma unroll
    for (int r = 0; r < 32; r += 8) {
      const int krow = k0 + tx, ncol = n0 + ty + r;
      float val = cB * tile[tx][ty + r];
      if (m >= 1 && krow == ncol) val += cA;
      dst[(size_t)ncol * NHID + krow] = (u16)f2bf(val);
    }
    return;
  }

  // ---- extract row ----
  int* s_cnt = (int*)smraw;
  const int i = bid - 3584;
  if (threadIdx.x == 0) *s_cnt = 0;
  __syncthreads();
  const uint4* row = (const uint4*)(adj + (size_t)i * N_NODES);
  for (int c = threadIdx.x; c < N_NODES / 4; c += 256) {
    uint4 v = row[c];
    if ((v.x | v.y | v.z | v.w) == 0u) continue;   // 0.0f bit pattern is 0
    unsigned int vals[4] = {v.x, v.y, v.z, v.w};
    #pragma unroll
    for (int e = 0; e < 4; ++e) {
      if (vals[e] != 0u) {
        int p = atomicAdd(s_cnt, 1);
        if (p < CAP) idx[(size_t)i * CAP + p] = c * 4 + e;
        atomicAdd(&colcnt[c * 4 + e], 1);
      }
    }
  }
  __syncthreads();
  if (threadIdx.x == 0) cnt[i] = min(*s_cnt, CAP);
}

// ---------------- MFMA GEMM, 64x64 tile, BK=64, 2-buf counted-vmcnt ---------
#define AS1 __attribute__((address_space(1)))
#define AS3 __attribute__((address_space(3)))

__device__ inline void load16(const void* g, void* l) {
  __builtin_amdgcn_global_load_lds((const AS1 void*)g, (AS3 void*)l, 16, 0, 0);
}

// MODE 0: v=relu(acc+bias); out0=H0, out1=Hs=dinv*v       [fc1]
// MODE 1: v=relu(acc);      out0=Hs=dinv*v                [layers 0..6]
// MODE 2: v=relu(acc);      out0=H (unscaled)             [layer 7]
// MODE 3: logits=acc+bias -> -log_softmax -> outF (f32)   [fc2, N=64]
// Pipeline per step t (2 bufs): B1 s_barrier (WAR) -> stage(t+1) ->
// s_waitcnt vmcnt(4) (own stage(t) landed, BEFORE barrier) -> B2 s_barrier
// (RAW: all waves' stage(t) landed) -> compute(t).
template<int MODE>
__global__ __launch_bounds__(256, 4)
void gemm_kernel(const u16* __restrict__ A, const u16* __restrict__ Bt,
                 const float* __restrict__ bias, const int* __restrict__ colc,
                 u16* __restrict__ out0, u16* __restrict__ out1,
                 float* __restrict__ outF)
{
  constexpr int K = 512;
  constexpr int N = (MODE == 3) ? NCLASS : 512;
  __shared__ u16 lds[2][2][64 * 64];   // [buf][A/B][tile] = 32 KB
  const int tid = threadIdx.x;
  const int wave = tid >> 6, lane = tid & 63;

  // chunked XCD swizzle (same-A-panel blocks share an XCD's L2; panel p
  // is served by XCD p/16)
  const int cpx = gridDim.x >> 3;
  const int logical = (blockIdx.x & 7) * cpx + (blockIdx.x >> 3);
  const int mblk = (MODE == 3) ? logical : (logical >> 3);
  const int nblk = (MODE == 3) ? 0 : (logical & 7);
  const int m0 = mblk * 64, n0 = nblk * 64;

  const int wr = wave >> 1, wc = wave & 1;
  const int lrow = lane & 15, lk = lane >> 4;

  f32x4 acc[2][2];
  #pragma unroll
  for (int a = 0; a < 2; ++a)
    #pragma unroll
    for (int b = 0; b < 2; ++b)
      acc[a][b] = (f32x4){0.f, 0.f, 0.f, 0.f};

  // rows of 64 k = 128 B = 8 chunks of 16 B; XOR swizzle j^(row&7) folded into
  // the per-lane GLOBAL source chunk, LDS dest linear (both-sides rule).
  auto stage = [&](int b, int ks) {
    #pragma unroll
    for (int r = 0; r < 2; ++r) {
      const int c = r * 256 + wave * 64 + lane;   // 512 chunks of 16B per tile
      const int row = c >> 3;
      const int sc = (c & 7) ^ (row & 7);
      load16(A  + (size_t)(m0 + row) * K + ks + sc * 8, &lds[b][0][(r * 256 + wave * 64) * 8]);
      load16(Bt + (size_t)(n0 + row) * K + ks + sc * 8, &lds[b][1][(r * 256 + wave * 64) * 8]);
    }
  };

  stage(0, 0);

  for (int t = 0; t < 8; ++t) {
    asm volatile("s_barrier" ::: "memory");           // B1: WAR on buf (t+1)&1
    if (t + 1 < 8) {
      stage((t + 1) & 1, (t + 1) * 64);
      asm volatile("s_waitcnt vmcnt(4)" ::: "memory"); // own stage(t) landed
    } else {
      asm volatile("s_waitcnt vmcnt(0)" ::: "memory");
    }
    asm volatile("s_barrier" ::: "memory");           // B2: RAW — whole buf t valid
    const int b = t & 1;
    const char* pA = (const char*)lds[b][0];
    const char* pB = (const char*)lds[b][1];
    bf16x8 af[2][2], bfr[2][2];
    #pragma unroll
    for (int mi = 0; mi < 2; ++mi) {
      const int row = wr * 32 + mi * 16 + lrow;
      #pragma unroll
      for (int ks2 = 0; ks2 < 2; ++ks2) {
        const int j = ks2 * 4 + lk;
        af[mi][ks2] = *(const bf16x8*)(pA + row * 128 + ((j ^ (row & 7)) * 16));
      }
    }
    #pragma unroll
    for (int ni = 0; ni < 2; ++ni) {
      const int row = wc * 32 + ni * 16 + lrow;
      #pragma unroll
      for (int ks2 = 0; ks2 < 2; ++ks2) {
        const int j = ks2 * 4 + lk;
        bfr[ni][ks2] = *(const bf16x8*)(pB + row * 128 + ((j ^ (row & 7)) * 16));
      }
    }
    #pragma unroll
    for (int ks2 = 0; ks2 < 2; ++ks2)
      #pragma unroll
      for (int mi = 0; mi < 2; ++mi)
        #pragma unroll
        for (int ni = 0; ni < 2; ++ni)
          acc[mi][ni] = __builtin_amdgcn_mfma_f32_16x16x32_bf16(af[mi][ks2], bfr[ni][ks2], acc[mi][ni], 0, 0, 0);
  }

  if (MODE != 3) {
    #pragma unroll
    for (int mi = 0; mi < 2; ++mi) {
      #pragma unroll
      for (int ni = 0; ni < 2; ++ni) {
        #pragma unroll
        for (int r = 0; r < 4; ++r) {
          const int row = m0 + wr * 32 + mi * 16 + lk * 4 + r;
          const int col = n0 + wc * 32 + ni * 16 + lrow;
          const size_t o = (size_t)row * N + col;
          float v = acc[mi][ni][r];
          if (MODE == 0) {
            v = fmaxf(v + bias[col], 0.f);
            const float di = rsqrtf((float)colc[row] + 1.0f);
            out0[o] = (u16)f2bf(v);                 // H0
            out1[o] = (u16)f2bf(di * v);            // Hs
          } else if (MODE == 1) {
            v = fmaxf(v, 0.f);
            const float di = rsqrtf((float)colc[row] + 1.0f);
            out0[o] = (u16)f2bf(di * v);
          } else {
            v = fmaxf(v, 0.f);
            out0[o] = (u16)f2bf(v);
          }
        }
      }
    }
  } else {
    __syncthreads();
    // stash logits (+bias) in LDS, then per-row softmax with lane = class
    float* Cf = (float*)&lds[0][0][0];              // 64x65 f32
    #pragma unroll
    for (int mi = 0; mi < 2; ++mi)
      #pragma unroll
      for (int ni = 0; ni < 2; ++ni)
        #pragma unroll
        for (int r = 0; r < 4; ++r) {
          const int row = wr * 32 + mi * 16 + lk * 4 + r;
          const int cc = wc * 32 + ni * 16 + lrow;
          if (cc < NCLASS) Cf[row * 65 + cc] = acc[mi][ni][r] + bias[cc];
        }
    __syncthreads();
    #pragma unroll 4
    for (int r = 0; r < 16; ++r) {
      const int row = wave * 16 + r;
      const float v = Cf[row * 65 + lane];
      float mx = v;
      #pragma unroll
      for (int off = 32; off > 0; off >>= 1) mx = fmaxf(mx, __shfl_xor(mx, off));
      float s = __expf(v - mx);
      #pragma unroll
      for (int off = 32; off > 0; off >>= 1) s += __shfl_xor(s, off);
      outF[(size_t)(m0 + row) * NCLASS + lane] = -(v - mx - logf(s));
    }
  }
}

// ---------------- SpMM: IR = 0.9*(P@H) + 0.1*H0, H pre-scaled ---------------
// XCD-aligned row ownership: block bid with c = bid&7, q = bid>>3 handles rows
// 1024c + 4q + wave — rows [1024c, 1024c+1024) = panels [16c, 16c+16) live on
// XCD c, matching the GEMM map (panel p served by XCD p/16). IR write -> GEMM
// A-read, Hs self-read, and H0 read are all local-L2. Gathers (7/8 remote) are
// unavoidable. 16-deep gather batches: a typical row (deg ~16.4) finishes its
// whole gather in ONE latency round instead of two.
__global__ __launch_bounds__(256)
void spmm_kernel(const u16* __restrict__ Hs, const u16* __restrict__ H0,
                 const int* __restrict__ colc, const int* __restrict__ idx,
                 const int* __restrict__ cnt, u16* __restrict__ IR)
{
  const int wave = threadIdx.x >> 6, lane = threadIdx.x & 63;
  const int c = blockIdx.x & 7, q = blockIdx.x >> 3;
  const int i = 1024 * c + 4 * q + wave;
  const int c0 = lane * 8;
  const int n = cnt[i];
  int jreg = 0;
  if (lane < n) jreg = idx[(size_t)i * CAP + lane] & (N_NODES - 1);

  float acc[8];
  #pragma unroll
  for (int e = 0; e < 8; ++e) acc[e] = 0.f;

  const int nn = min(n, 64);
  int t = 0;
  for (; t + 16 <= nn; t += 16) {        // 16 gathers in flight (typ. one round)
    bf16x8 v[16];
    #pragma unroll
    for (int u = 0; u < 16; ++u) {
      const int j = __shfl(jreg, t + u);
      v[u] = *(const bf16x8*)&Hs[(size_t)j * NHID + c0];
    }
    #pragma unroll
    for (int u = 0; u < 16; ++u)
      #pragma unroll
      for (int e = 0; e < 8; ++e)
        acc[e] += bf2f(v[u][e]);
  }
  for (; t + 8 <= nn; t += 8) {          // 8 in flight
    bf16x8 v[8];
    #pragma unroll
    for (int u = 0; u < 8; ++u) {
      const int j = __shfl(jreg, t + u);
      v[u] = *(const bf16x8*)&Hs[(size_t)j * NHID + c0];
    }
    #pragma unroll
    for (int u = 0; u < 8; ++u)
      #pragma unroll
      for (int e = 0; e < 8; ++e)
        acc[e] += bf2f(v[u][e]);
  }
  for (; t < nn; ++t) {
    const int j = __shfl(jreg, t);
    bf16x8 v = *(const bf16x8*)&Hs[(size_t)j * NHID + c0];
    #pragma unroll
    for (int e = 0; e < 8; ++e) acc[e] += bf2f(v[e]);
  }
  for (; t < n; ++t) {                   // n > 64: essentially never
    const int j = idx[(size_t)i * CAP + t] & (N_NODES - 1);
    bf16x8 v = *(const bf16x8*)&Hs[(size_t)j * NHID + c0];
    #pragma unroll
    for (int e = 0; e < 8; ++e) acc[e] += bf2f(v[e]);
  }

  const float di = rsqrtf((float)colc[i] + 1.0f);
  bf16x8 self = *(const bf16x8*)&Hs[(size_t)i * NHID + c0];
  bf16x8 h0   = *(const bf16x8*)&H0[(size_t)i * NHID + c0];
  bf16x8 ov;
  #pragma unroll
  for (int e = 0; e < 8; ++e) {
    float v = 0.9f * di * (acc[e] + bf2f(self[e])) + 0.1f * bf2f(h0[e]);
    ov[e] = f2bf(v);
  }
  *(bf16x8*)&IR[(size_t)i * NHID + c0] = ov;
}

// ---------------- launch -----------------------------------------------------
extern "C" void kernel_launch(void* const* d_in, const int* in_sizes, int n_in,
                              void* d_out, int out_size, void* d_ws, size_t ws_size,
                              hipStream_t stream)
{
  const float* x     = (const float*)d_in[0];
  const float* adj   = (const float*)d_in[1];
  const float* fc1W  = (const float*)d_in[2];
  const float* fc1b  = (const float*)d_in[3];
  const float* convW = (const float*)d_in[4];
  const float* fc2W  = (const float*)d_in[5];
  const float* fc2b  = (const float*)d_in[6];
  float* out = (float*)d_out;

  char* ws = (char*)d_ws;
  size_t off = 0;
  auto alloc = [&](size_t bytes) -> void* {
    void* p = ws + off;
    off = (off + bytes + 255) & ~(size_t)255;
    return p;
  };
  u16*   xb   = (u16*)alloc((size_t)N_NODES * NFEAT * 2);
  u16*   Wt   = (u16*)alloc((size_t)9 * NHID * NHID * 2);
  u16*   Wt2  = (u16*)alloc((size_t)NCLASS * NHID * 2);
  u16*   H0   = (u16*)alloc((size_t)N_NODES * NHID * 2);
  u16*   HsA  = (u16*)alloc((size_t)N_NODES * NHID * 2);
  u16*   HsB  = (u16*)alloc((size_t)N_NODES * NHID * 2);
  u16*   IR   = (u16*)alloc((size_t)N_NODES * NHID * 2);
  int*   idx  = (int*)alloc((size_t)N_NODES * CAP * 4);
  int*   cnt  = (int*)alloc((size_t)N_NODES * 4);
  int*   colc = (int*)alloc((size_t)N_NODES * 4);

  Coefs co;
  for (int i = 0; i < NLAYERS; ++i) {
    const double beta = log(0.5 / (double)(i + 1) + 1.0);
    co.cA[i] = (float)(1.0 - beta);
    co.cB[i] = (float)beta;
  }

  hipMemsetAsync(colc, 0, (size_t)N_NODES * 4, stream);
  front_kernel<<<1024 + 2560 + 8192, 256, 0, stream>>>(
      adj, idx, cnt, colc, x, xb, fc1W, convW, fc2W, Wt, Wt2, co);

  // fc1: H0 = relu(x@W+b), Hs = dinv*H0
  gemm_kernel<0><<<1024, 256, 0, stream>>>(xb, Wt, fc1b, colc, H0, HsA, nullptr);

  const u16* Hin = HsA;
  for (int i = 0; i < NLAYERS; ++i) {
    spmm_kernel<<<N_NODES / 4, 256, 0, stream>>>(Hin, H0, colc, idx, cnt, IR);
    u16* Hout = (Hin == HsA) ? HsB : HsA;
    if (i < NLAYERS - 1)
      gemm_kernel<1><<<1024, 256, 0, stream>>>(
          IR, Wt + (size_t)(i + 1) * NHID * NHID, nullptr, colc, Hout, nullptr, nullptr);
    else
      gemm_kernel<2><<<1024, 256, 0, stream>>>(
          IR, Wt + (size_t)(i + 1) * NHID * NHID, nullptr, colc, Hout, nullptr, nullptr);
    Hin = Hout;
  }

  // fc2 + -log_softmax (MFMA, N=64)
  gemm_kernel<3><<<128, 256, 0, stream>>>((const u16*)Hin, Wt2, fc2b, nullptr, nullptr, nullptr, out);
}